// Round 4
// baseline (88.824 us; speedup 1.0000x reference)
//
#include <hip/hip_runtime.h>

// Problem constants (fixed by setup_inputs): B=8, N=4096, K=3, V=100000,
// H=1024, SEQ=2048. H hard-coded; rest derived from in_sizes.
#define CAP 8    // max sets per (b, pos); dataset has exactly 2
#define RPB 16   // rows per gather block (grid = nrows/RPB = 1024, all resident)

// Phase 1: scatter each set's token ids into the per-(b,pos) token table.
__global__ void build_map_kernel(const int* __restrict__ pos_ids,
                                 const int* __restrict__ tok,
                                 int total, int n_per, int seq, int K,
                                 int* __restrict__ counts,
                                 int* __restrict__ toktab) {
    int i = blockIdx.x * blockDim.x + threadIdx.x;
    if (i >= total) return;
    int b = i / n_per;
    int p = pos_ids[i];
    if ((unsigned)p >= (unsigned)seq) return;
    int bp = b * seq + p;
    int c = atomicAdd(&counts[bp], 1);
    if (c < CAP) {
        int* dst = toktab + (size_t)bp * (CAP * K) + c * K;
        for (int k = 0; k < K; ++k) dst[k] = tok[i * K + k];
    }
}

#define SORT2(a, b) { int _lo = min(a, b); int _hi = max(a, b); a = _lo; b = _hi; }

// Phase 1.5: sort each row's token list ascending (deterministic FP order AND
// rank-phase locality: token rank correlates with token value/quantile).
__global__ void sort_rows_kernel(const int* __restrict__ counts,
                                 int* __restrict__ toktab,
                                 int nrows, int K) {
    int i = blockIdx.x * blockDim.x + threadIdx.x;
    if (i >= nrows) return;
    int cnt = counts[i];
    int ce = cnt < CAP ? cnt : CAP;
    int n = ce * K;
    int stride = CAP * K;
    int* row = toktab + (size_t)i * stride;
    if (n == 6) {
        int t0=row[0],t1=row[1],t2=row[2],t3=row[3],t4=row[4],t5=row[5];
        SORT2(t1,t2) SORT2(t4,t5) SORT2(t0,t2) SORT2(t3,t5)
        SORT2(t0,t1) SORT2(t3,t4) SORT2(t1,t4) SORT2(t0,t3)
        SORT2(t2,t5) SORT2(t1,t3) SORT2(t2,t4) SORT2(t2,t3)
        row[0]=t0;row[1]=t1;row[2]=t2;row[3]=t3;row[4]=t4;row[5]=t5;
    } else if (n > 1) {
        int tmp[CAP * 8];
        if (n > CAP * 8) n = CAP * 8;
        for (int j = 0; j < n; ++j) tmp[j] = row[j];
        for (int a = 1; a < n; ++a) {
            int v = tmp[a]; int q = a - 1;
            while (q >= 0 && tmp[q] > v) { tmp[q + 1] = tmp[q]; --q; }
            tmp[q + 1] = v;
        }
        for (int j = 0; j < n; ++j) row[j] = tmp[j];
    }
}

// Phase 2: one block per RPB output rows, all blocks co-resident. March
// rank-major (j outer) so every block reads the same token-quantile band at
// the same time -> instantaneous W working set ~130 MB, fits L3, repeats hit.
__global__ __launch_bounds__(256, 4)
void gather_out_kernel(const float* __restrict__ W,
                       const int* __restrict__ counts,
                       const int* __restrict__ toktab,
                       float* __restrict__ out,
                       int K, int H, int nrows) {
    int r0 = blockIdx.x * RPB;
    int h = threadIdx.x * 4;  // blockDim.x == H/4
    int stride = CAP * K;

    int cnt[RPB];
    bool allsix = true;
    #pragma unroll
    for (int r = 0; r < RPB; ++r) {
        int row = r0 + r;
        cnt[r] = (row < nrows) ? counts[row] : 0;
        int ce = cnt[r] < CAP ? cnt[r] : CAP;
        if (ce * K != 6) allsix = false;
    }

    float4 acc[RPB];
    #pragma unroll
    for (int r = 0; r < RPB; ++r) acc[r] = make_float4(0.f, 0.f, 0.f, 0.f);

    if (allsix) {
        // Fast path: rank-phase-ordered gather, 16 independent loads per rank.
        #pragma unroll
        for (int j = 0; j < 6; ++j) {
            #pragma unroll
            for (int r = 0; r < RPB; ++r) {
                int t = toktab[(size_t)(r0 + r) * stride + j];  // uniform
                const float4 v = *(const float4*)(W + (size_t)t * H + h);
                acc[r].x += v.x; acc[r].y += v.y;
                acc[r].z += v.z; acc[r].w += v.w;
            }
        }
    } else {
        // General path: per-row variable count, still ascending-token order.
        #pragma unroll
        for (int r = 0; r < RPB; ++r) {
            int ce = cnt[r] < CAP ? cnt[r] : CAP;
            int ntok = ce * K;
            for (int j = 0; j < ntok; ++j) {
                int t = toktab[(size_t)(r0 + r) * stride + j];
                const float4 v = *(const float4*)(W + (size_t)t * H + h);
                acc[r].x += v.x; acc[r].y += v.y;
                acc[r].z += v.z; acc[r].w += v.w;
            }
        }
    }

    #pragma unroll
    for (int r = 0; r < RPB; ++r) {
        int row = r0 + r;
        if (row >= nrows) continue;
        float denom = (float)K * (float)(cnt[r] > 0 ? cnt[r] : 1);
        float s = 1.0f / denom;
        float* op = out + (size_t)row * H + h;
        __builtin_nontemporal_store(acc[r].x * s, op + 0);
        __builtin_nontemporal_store(acc[r].y * s, op + 1);
        __builtin_nontemporal_store(acc[r].z * s, op + 2);
        __builtin_nontemporal_store(acc[r].w * s, op + 3);
    }
}

extern "C" void kernel_launch(void* const* d_in, const int* in_sizes, int n_in,
                              void* d_out, int out_size, void* d_ws, size_t ws_size,
                              hipStream_t stream) {
    const int*   pos_ids = (const int*)d_in[0];   // [B*N] int32
    const int*   tok     = (const int*)d_in[1];   // [B*N*K] int32
    // d_in[2]: offsets [B,2]; d_in[3]: seq_len scalar (derived on host)
    const float* W       = (const float*)d_in[4]; // [V*H] f32
    float*       out     = (float*)d_out;         // [B*SEQ*H] f32

    const int B     = in_sizes[2] / 2;
    const int total = in_sizes[0];        // B*N sets
    const int n_per = total / B;          // N
    const int K     = in_sizes[1] / total;
    const int H     = 1024;
    const int seq   = out_size / (B * H);
    const int nrows = B * seq;

    int* counts = (int*)d_ws;                               // [nrows]
    int* toktab = counts + (size_t)nrows;                   // [nrows*CAP*K]

    hipMemsetAsync(counts, 0, (size_t)nrows * sizeof(int), stream);

    int bthreads = 256;
    int bblocks  = (total + bthreads - 1) / bthreads;
    build_map_kernel<<<bblocks, bthreads, 0, stream>>>(pos_ids, tok, total,
                                                       n_per, seq, K,
                                                       counts, toktab);

    int sblocks = (nrows + bthreads - 1) / bthreads;
    sort_rows_kernel<<<sblocks, bthreads, 0, stream>>>(counts, toktab,
                                                       nrows, K);

    int gblocks = (nrows + RPB - 1) / RPB;
    gather_out_kernel<<<gblocks, H / 4, 0, stream>>>(W, counts, toktab,
                                                     out, K, H, nrows);
}